// Round 1
// baseline (517.047 us; speedup 1.0000x reference)
//
#include <hip/hip_runtime.h>
#include <math.h>

#define NN 8192
#define NF 128

// ws layout (float indices):
// dinv   [0, 8192)
// c      [8192, 16384)          zeroed, atomic colsum accum -> finalized c
// s1     [16384, 98304)         8192*10
// h      [98304, 180224)        8192*10
// accum  [180224, 180240)       10 used (zeroed)
// Zcount int at 180240          (zeroed)
// Zlist  ints [180244, 180244+8192)
// total ~754 KB

// ---------------------------------------------------------------------------
// Pass A: per-row degree -> dinv (exact), plus unweighted column sums into c
// via atomics (c_j corrected to dinv-weighted sums in kC). Also records rows
// whose degree != N (rows of adj containing an exact 0.0).
// grid 256 blocks x 256 threads, 32 rows/block; thread t owns fixed j-set
// {(it*256+t)*4 .. +3} across all rows -> column sums live in 8 float4 regs.
// ---------------------------------------------------------------------------
__global__ __launch_bounds__(256) void kA(const float* __restrict__ adj,
                                          float* __restrict__ dinv,
                                          float* __restrict__ c0,
                                          int* __restrict__ Zcount,
                                          int* __restrict__ Zlist) {
    const int t = threadIdx.x;
    const int lane = t & 63, wid = t >> 6;
    const int rowBase = blockIdx.x * 32;
    float4 csum[8];
#pragma unroll
    for (int q = 0; q < 8; q++) csum[q] = make_float4(0.f, 0.f, 0.f, 0.f);
    __shared__ int wsum[4];

    for (int r = 0; r < 32; r++) {
        const int i = rowBase + r;
        const float4* arow = (const float4*)(adj + (size_t)i * NN);
        int cnt = 0;
#pragma unroll
        for (int it = 0; it < 8; it++) {
            float4 a = arow[it * 256 + t];
            csum[it].x += a.x; csum[it].y += a.y;
            csum[it].z += a.z; csum[it].w += a.w;
            cnt += (a.x > 0.f) + (a.y > 0.f) + (a.z > 0.f) + (a.w > 0.f);
        }
#pragma unroll
        for (int off = 32; off > 0; off >>= 1) cnt += __shfl_xor(cnt, off, 64);
        if (lane == 0) wsum[wid] = cnt;
        __syncthreads();
        if (t == 0) {
            int d = wsum[0] + wsum[1] + wsum[2] + wsum[3];
            dinv[i] = rsqrtf((float)d);
            if (d != NN) { int p = atomicAdd(Zcount, 1); Zlist[p] = i; }
        }
        __syncthreads();
    }
    // flush column-sum partials (disjoint j within a block; contention only
    // across the 256 blocks)
#pragma unroll
    for (int it = 0; it < 8; it++) {
        int j = (it * 256 + t) * 4;
        atomicAdd(&c0[j + 0], csum[it].x);
        atomicAdd(&c0[j + 1], csum[it].y);
        atomicAdd(&c0[j + 2], csum[it].z);
        atomicAdd(&c0[j + 3], csum[it].w);
    }
}

// ---------------------------------------------------------------------------
// Finalize c_j = dinv0*colsum_j + sum_{i in Z} (dinv_i - dinv0) * adj[i][j]
// Exact: rows not in Z have dinv_i == rsqrtf(N) == dinv0.
// ---------------------------------------------------------------------------
__global__ __launch_bounds__(256) void kC(const float* __restrict__ adj,
                                          const float* __restrict__ dinv,
                                          float* __restrict__ c0,
                                          const int* __restrict__ Zcount,
                                          const int* __restrict__ Zlist) {
    int j = blockIdx.x * 256 + threadIdx.x;
    const float dinv0 = rsqrtf((float)NN);
    float v = c0[j] * dinv0;
    int zc = *Zcount;
    for (int p = 0; p < zc; p++) {
        int zi = Zlist[p];
        v += (dinv[zi] - dinv0) * adj[(size_t)zi * NN + j];
    }
    c0[j] = v;
}

// ---------------------------------------------------------------------------
// s1[j,k] = (x[j,:] @ W1[:,k]) * dinv[j]   ([8192,128]@[128,10])
// one thread per (j,k); W1 staged in LDS.
// ---------------------------------------------------------------------------
__global__ __launch_bounds__(256) void kS1(const float* __restrict__ x,
                                           const float* __restrict__ W1,
                                           const float* __restrict__ dinv,
                                           float* __restrict__ s1) {
    __shared__ float sW[NF * 10];
    for (int i = threadIdx.x; i < NF * 10; i += 256) sW[i] = W1[i];
    __syncthreads();
    int tid = blockIdx.x * 256 + threadIdx.x;   // = j*10 + k, 81920 total
    int j = tid / 10, k = tid % 10;
    const float4* xr = (const float4*)(x + (size_t)j * NF);
    float s = 0.f;
#pragma unroll
    for (int f4 = 0; f4 < 32; f4++) {
        float4 a = xr[f4];
        s += a.x * sW[(f4 * 4 + 0) * 10 + k] + a.y * sW[(f4 * 4 + 1) * 10 + k]
           + a.z * sW[(f4 * 4 + 2) * 10 + k] + a.w * sW[(f4 * 4 + 3) * 10 + k];
    }
    s1[tid] = s * dinv[j];
}

// ---------------------------------------------------------------------------
// Layer-1 matvec: h[i,k] = relu(dinv_i*( sum_j adj[i,j]*s1[j,k] + s1[i,k]) + b1[k])
// grid 512 x 256; 4 waves/block; each wave register-tiles 4 rows so each
// 160 B s1 chunk (4 j's x 10 k) feeds 160 FMAs. All loads coalesced float4.
// ---------------------------------------------------------------------------
__global__ __launch_bounds__(256) void kP(const float* __restrict__ adj,
                                          const float* __restrict__ s1,
                                          const float* __restrict__ dinv,
                                          const float* __restrict__ b1,
                                          float* __restrict__ h) {
    const int t = threadIdx.x;
    const int lane = t & 63, wid = t >> 6;
    const int i0 = blockIdx.x * 16 + wid * 4;
    float acc[4][10];
#pragma unroll
    for (int r = 0; r < 4; r++)
#pragma unroll
        for (int k = 0; k < 10; k++) acc[r][k] = 0.f;

    const float4* a0p = (const float4*)(adj + (size_t)(i0 + 0) * NN);
    const float4* a1p = (const float4*)(adj + (size_t)(i0 + 1) * NN);
    const float4* a2p = (const float4*)(adj + (size_t)(i0 + 2) * NN);
    const float4* a3p = (const float4*)(adj + (size_t)(i0 + 3) * NN);

    for (int it = 0; it < 32; it++) {
        int vi = it * 64 + lane;                 // float4 index; j4 = vi*4
        float4 a0 = a0p[vi], a1 = a1p[vi], a2 = a2p[vi], a3 = a3p[vi];
        const float4* sp = (const float4*)(s1 + (size_t)vi * 40);
        float sv[40];
#pragma unroll
        for (int q = 0; q < 10; q++) {
            float4 v = sp[q];
            sv[q * 4 + 0] = v.x; sv[q * 4 + 1] = v.y;
            sv[q * 4 + 2] = v.z; sv[q * 4 + 3] = v.w;
        }
        // sv[jj*10+k] = s1[j4+jj][k]
#pragma unroll
        for (int k = 0; k < 10; k++) {
            acc[0][k] += a0.x * sv[k] + a0.y * sv[10 + k] + a0.z * sv[20 + k] + a0.w * sv[30 + k];
            acc[1][k] += a1.x * sv[k] + a1.y * sv[10 + k] + a1.z * sv[20 + k] + a1.w * sv[30 + k];
            acc[2][k] += a2.x * sv[k] + a2.y * sv[10 + k] + a2.z * sv[20 + k] + a2.w * sv[30 + k];
            acc[3][k] += a3.x * sv[k] + a3.y * sv[10 + k] + a3.z * sv[20 + k] + a3.w * sv[30 + k];
        }
    }
    // all-reduce each of the 40 partials across the wave
#pragma unroll
    for (int r = 0; r < 4; r++)
#pragma unroll
        for (int k = 0; k < 10; k++)
#pragma unroll
            for (int off = 32; off > 0; off >>= 1)
                acc[r][k] += __shfl_xor(acc[r][k], off, 64);

    if (lane == 0) {
#pragma unroll
        for (int r = 0; r < 4; r++) {
            int i = i0 + r;
            float di = dinv[i];
#pragma unroll
            for (int k = 0; k < 10; k++) {
                float v = di * (acc[r][k] + s1[i * 10 + k]) + b1[k];
                h[i * 10 + k] = fmaxf(v, 0.f);
            }
        }
    }
}

// ---------------------------------------------------------------------------
// Final reductions: s2[j,k] = (h[j,:]@W2[:,k])*dinv_j (k<5)
// accum[k]   += c_j   * s2[j,k]   (= sum_i dinv_i (adj@s2)[i,k])
// accum[5+k] += dinv_j* s2[j,k]   (= sum_i dinv_i s2[i,k])
// ---------------------------------------------------------------------------
__global__ __launch_bounds__(256) void kF1(const float* __restrict__ h,
                                           const float* __restrict__ dinv,
                                           const float* __restrict__ c0,
                                           const float* __restrict__ W2,
                                           float* __restrict__ accum) {
    int j = blockIdx.x * 256 + threadIdx.x;
    float hv[10];
#pragma unroll
    for (int m = 0; m < 10; m++) hv[m] = h[j * 10 + m];
    float dj = dinv[j], cj = c0[j];
    float p[10];
#pragma unroll
    for (int k = 0; k < 5; k++) {
        float s = 0.f;
#pragma unroll
        for (int m = 0; m < 10; m++) s += hv[m] * W2[m * 5 + k];
        s *= dj;
        p[k] = cj * s;
        p[5 + k] = dj * s;
    }
#pragma unroll
    for (int q = 0; q < 10; q++) {
        float v = p[q];
#pragma unroll
        for (int off = 32; off > 0; off >>= 1) v += __shfl_xor(v, off, 64);
        if ((threadIdx.x & 63) == 0) atomicAdd(&accum[q], v);
    }
}

// ---------------------------------------------------------------------------
// z = relu((S1+S2)/N + b2); z2 = relu(z@fc1_W+fc1_b); y = sigmoid(z2@fc_W+fc_b)
// out = [z(5), y(2)]
// ---------------------------------------------------------------------------
__global__ void kF2(const float* __restrict__ accum, const float* __restrict__ b2,
                    const float* __restrict__ fc1W, const float* __restrict__ fc1b,
                    const float* __restrict__ fcW, const float* __restrict__ fcb,
                    float* __restrict__ out) {
    if (threadIdx.x == 0 && blockIdx.x == 0) {
        float z[5];
        for (int k = 0; k < 5; k++) {
            float v = (accum[k] + accum[5 + k]) * (1.f / (float)NN) + b2[k];
            z[k] = fmaxf(v, 0.f);
            out[k] = z[k];
        }
        float z2[5];
        for (int m = 0; m < 5; m++) {
            float v = fc1b[m];
            for (int k = 0; k < 5; k++) v += z[k] * fc1W[k * 5 + m];
            z2[m] = fmaxf(v, 0.f);
        }
        for (int n = 0; n < 2; n++) {
            float v = fcb[n];
            for (int m = 0; m < 5; m++) v += z2[m] * fcW[m * 2 + n];
            out[5 + n] = 1.f / (1.f + expf(-v));
        }
    }
}

extern "C" void kernel_launch(void* const* d_in, const int* in_sizes, int n_in,
                              void* d_out, int out_size, void* d_ws, size_t ws_size,
                              hipStream_t stream) {
    const float* x    = (const float*)d_in[0];
    const float* adj  = (const float*)d_in[1];
    const float* W1   = (const float*)d_in[2];
    const float* b1   = (const float*)d_in[3];
    const float* W2   = (const float*)d_in[4];
    const float* b2   = (const float*)d_in[5];
    const float* fc1W = (const float*)d_in[6];
    const float* fc1b = (const float*)d_in[7];
    const float* fcW  = (const float*)d_in[8];
    const float* fcb  = (const float*)d_in[9];
    (void)in_sizes; (void)n_in; (void)out_size; (void)ws_size;

    float* ws    = (float*)d_ws;
    float* dinv  = ws;
    float* c0    = ws + 8192;
    float* s1    = ws + 16384;
    float* h     = ws + 98304;
    float* accum = ws + 180224;
    int*   Zcount = (int*)(ws + 180240);
    int*   Zlist  = (int*)(ws + 180244);
    float* out = (float*)d_out;

    // zero the atomic accumulators (ws is poisoned 0xAA before every launch)
    hipMemsetAsync(c0, 0, 8192 * sizeof(float), stream);
    hipMemsetAsync(accum, 0, 20 * sizeof(float), stream);  // accum[10..] + Zcount

    kA <<<256, 256, 0, stream>>>(adj, dinv, c0, Zcount, Zlist);
    kC <<<32,  256, 0, stream>>>(adj, dinv, c0, Zcount, Zlist);
    kS1<<<320, 256, 0, stream>>>(x, W1, dinv, s1);
    kP <<<512, 256, 0, stream>>>(adj, s1, dinv, b1, h);
    kF1<<<32,  256, 0, stream>>>(h, dinv, c0, W2, accum);
    kF2<<<1,   64,  0, stream>>>(accum, b2, fc1W, fc1b, fcW, fcb, out);
}